// Round 1
// baseline (355.181 us; speedup 1.0000x reference)
//
#include <hip/hip_runtime.h>
#include <math.h>

#define DD 2048
#define HH 4096
#define NSTEPS 16
#define KK 4

// workspace float offsets
#define OFF_CAT    0        // h[4096], l[2048], conv[1]  (6145 used, pad to 6400)
#define OFF_GI_H   6400     // 12288
#define OFF_GH_H   18688    // 12288
#define OFF_GI_L   30976    // 6144
#define OFF_GH_L   37120    // 6144
#define OFF_DIR    43264    // 2048
#define OFF_RES    45312    // 2048
#define OFF_RESULT 47360    // 2048
#define OFF_SCAL   49408    // [0]cum [1]weight [2]best [3]mom [4]active [5]do_reset

static __device__ __forceinline__ float sigf(float x) { return 1.0f / (1.0f + expf(-x)); }

static __device__ __forceinline__ float wred(float s) {
#pragma unroll
  for (int off = 32; off; off >>= 1) s += __shfl_down(s, off);
  return s;
}

// y[row] = act( dot(W[row,:], x) + b[row] ); wave-per-row, float4 loads
__global__ __launch_bounds__(256) void k_matvec(
    const float* __restrict__ W, const float4* __restrict__ x,
    const float* __restrict__ b, float* __restrict__ y,
    int rows, int n4, int act, const float* __restrict__ gate) {
  if (gate && *gate == 0.0f) return;
  int row = (int)((blockIdx.x * blockDim.x + threadIdx.x) >> 6);
  if (row >= rows) return;
  int lane = threadIdx.x & 63;
  const float4* Wr = (const float4*)W + (size_t)row * n4;
  float s = 0.0f;
  for (int i = lane; i < n4; i += 64) {
    float4 w = Wr[i], v = x[i];
    s = fmaf(w.x, v.x, s); s = fmaf(w.y, v.y, s);
    s = fmaf(w.z, v.z, s); s = fmaf(w.w, v.w, s);
  }
  s = wred(s);
  if (lane == 0) {
    s += b[row];
    if (act) s = tanhf(s);
    y[row] = s;
  }
}

// h-GRU matvecs fused: rows [0,12288): gi = wih @ concat(q,l) + bih
//                      rows [12288,24576): gh = whh @ h + bhh
__global__ __launch_bounds__(256) void k_hgru_mm(
    const float* __restrict__ wih, const float* __restrict__ whh,
    const float4* __restrict__ q4, const float4* __restrict__ l4,
    const float4* __restrict__ h4,
    const float* __restrict__ bih, const float* __restrict__ bhh,
    float* __restrict__ gi, float* __restrict__ gh,
    const float* __restrict__ gate) {
  if (*gate == 0.0f) return;
  int row = (int)((blockIdx.x * blockDim.x + threadIdx.x) >> 6);
  int lane = threadIdx.x & 63;
  float s = 0.0f;
  if (row < 3 * HH) {
    const float4* Wr = (const float4*)wih + (size_t)row * 1024;  // 4096 cols
    for (int i = lane; i < 1024; i += 64) {
      float4 w = Wr[i];
      float4 v = (i < 512) ? q4[i] : l4[i - 512];
      s = fmaf(w.x, v.x, s); s = fmaf(w.y, v.y, s);
      s = fmaf(w.z, v.z, s); s = fmaf(w.w, v.w, s);
    }
    s = wred(s);
    if (lane == 0) gi[row] = s + bih[row];
  } else {
    int r = row - 3 * HH;
    if (r >= 3 * HH) return;
    const float4* Wr = (const float4*)whh + (size_t)r * 1024;    // 4096 cols
    for (int i = lane; i < 1024; i += 64) {
      float4 w = Wr[i], v = h4[i];
      s = fmaf(w.x, v.x, s); s = fmaf(w.y, v.y, s);
      s = fmaf(w.z, v.z, s); s = fmaf(w.w, v.w, s);
    }
    s = wred(s);
    if (lane == 0) gh[r] = s + bhh[r];
  }
}

// l-GRU matvecs fused: rows [0,6144): gi = wih @ directive + bih
//                      rows [6144,12288): gh = whh @ l + bhh
__global__ __launch_bounds__(256) void k_lgru_mm(
    const float* __restrict__ wih, const float* __restrict__ whh,
    const float4* __restrict__ dir4, const float4* __restrict__ l4,
    const float* __restrict__ bih, const float* __restrict__ bhh,
    float* __restrict__ gi, float* __restrict__ gh,
    const float* __restrict__ gate) {
  if (*gate == 0.0f) return;
  int row = (int)((blockIdx.x * blockDim.x + threadIdx.x) >> 6);
  int lane = threadIdx.x & 63;
  const float* W; const float4* x; const float* b; float* y; int r;
  if (row < 3 * DD) { W = wih; x = dir4; b = bih; y = gi; r = row; }
  else { r = row - 3 * DD; if (r >= 3 * DD) return; W = whh; x = l4; b = bhh; y = gh; }
  const float4* Wr = (const float4*)W + (size_t)r * 512;  // 2048 cols
  float s = 0.0f;
  for (int i = lane; i < 512; i += 64) {
    float4 w = Wr[i], v = x[i];
    s = fmaf(w.x, v.x, s); s = fmaf(w.y, v.y, s);
    s = fmaf(w.z, v.z, s); s = fmaf(w.w, v.w, s);
  }
  s = wred(s);
  if (lane == 0) y[r] = s + b[r];
}

// h'[i] = (1-z)*n + z*h[i]
__global__ __launch_bounds__(256) void k_gru_combine(
    const float* __restrict__ gi, const float* __restrict__ gh,
    float* __restrict__ hl, int n, const float* __restrict__ gate) {
  if (*gate == 0.0f) return;
  int i = blockIdx.x * blockDim.x + threadIdx.x;
  if (i >= n) return;
  float r = sigf(gi[i] + gh[i]);
  float z = sigf(gi[n + i] + gh[n + i]);
  float nn = tanhf(gi[2 * n + i] + r * gh[2 * n + i]);
  hl[i] = (1.0f - z) * nn + z * hl[i];
}

// single-block: conv+mom, halt, p, result+=p*res, weight/cum/best, reset_prob, flags
__global__ __launch_bounds__(256) void k_finalize(
    float* __restrict__ cat, const float* __restrict__ res,
    const float* __restrict__ conv_w, const float* __restrict__ conv_b,
    const float* __restrict__ halt_w, const float* __restrict__ halt_b,
    const float* __restrict__ reset_w, const float* __restrict__ reset_b,
    float* __restrict__ scal, float* __restrict__ result, int step_idx) {
  __shared__ float sbuf[8];
  __shared__ float s_p;
  int tid = threadIdx.x;
  if (scal[4] == 0.0f) {            // inactive: nothing changes except clearing reset flag
    if (tid == 0) scal[5] = 0.0f;
    return;
  }
  // conv = sigmoid(h_conv_w @ h + b); mom update
  float s = 0.0f;
  for (int i = tid; i < HH; i += 256) s += conv_w[i] * cat[i];
  s = wred(s);
  if ((tid & 63) == 0) sbuf[tid >> 6] = s;
  __syncthreads();
  if (tid == 0) {
    float dot = sbuf[0] + sbuf[1] + sbuf[2] + sbuf[3];
    float raw = sigf(dot + conv_b[0]);
    float mom = 0.9f * scal[3] + 0.1f * raw;
    scal[3] = mom;
    cat[HH + DD] = mom;             // conv slot for reset concat
  }
  __syncthreads();
  // halt dot over [h,l] (6144), reset dot over [h,l,conv] (6145)
  float sh = 0.0f, sr = 0.0f;
  for (int i = tid; i < HH + DD; i += 256) sh += halt_w[i] * cat[i];
  for (int i = tid; i < HH + DD + 1; i += 256) sr += reset_w[i] * cat[i];
  sh = wred(sh); sr = wred(sr);
  __syncthreads();
  if ((tid & 63) == 0) { sbuf[tid >> 6] = sh; sbuf[4 + (tid >> 6)] = sr; }
  __syncthreads();
  if (tid == 0) {
    float halt = sigf(sbuf[0] + sbuf[1] + sbuf[2] + sbuf[3] + halt_b[0]);
    float rdot = sbuf[4] + sbuf[5] + sbuf[6] + sbuf[7] + reset_b[0];
    float cum = scal[0];
    float p = fminf(halt, 1.0f - cum);
    scal[1] += p;                   // weight
    cum += p; scal[0] = cum;
    float conv = scal[3];
    if (conv > scal[2] + 0.01f) scal[2] = conv;   // best
    bool brk = cum > 0.95f;
    float rp = sigf(rdot);
    scal[5] = (!brk && rp > 0.7f && step_idx > KK) ? 1.0f : 0.0f;
    scal[4] = brk ? 0.0f : 1.0f;
    s_p = p;
  }
  __syncthreads();
  float p = s_p;
  for (int i = tid; i < DD; i += 256) result[i] += p * res[i];
}

__global__ __launch_bounds__(256) void k_init(float* __restrict__ ws) {
  int i = blockIdx.x * blockDim.x + threadIdx.x;
  if (i < HH + DD + 1) ws[OFF_CAT + i] = 0.0f;         // h, l, conv
  if (i < DD) ws[OFF_RESULT + i] = 0.0f;
  if (i < 8) ws[OFF_SCAL + i] = (i == 4) ? 1.0f : 0.0f; // active=1, rest 0
}

__global__ __launch_bounds__(256) void k_out(
    const float* __restrict__ result, const float* __restrict__ scal,
    float* __restrict__ out) {
  int i = blockIdx.x * blockDim.x + threadIdx.x;
  if (i < DD) out[i] = result[i] / fmaxf(scal[1], 1e-8f);
}

extern "C" void kernel_launch(void* const* d_in, const int* in_sizes, int n_in,
                              void* d_out, int out_size, void* d_ws, size_t ws_size,
                              hipStream_t stream) {
  const float* query     = (const float*)d_in[0];
  const float* h_gru_wih = (const float*)d_in[1];
  const float* h_gru_whh = (const float*)d_in[2];
  const float* h_gru_bih = (const float*)d_in[3];
  const float* h_gru_bhh = (const float*)d_in[4];
  const float* l_gru_wih = (const float*)d_in[5];
  const float* l_gru_whh = (const float*)d_in[6];
  const float* l_gru_bih = (const float*)d_in[7];
  const float* l_gru_bhh = (const float*)d_in[8];
  const float* h_dir_w   = (const float*)d_in[9];
  const float* h_dir_b   = (const float*)d_in[10];
  const float* h_conv_w  = (const float*)d_in[11];
  const float* h_conv_b  = (const float*)d_in[12];
  const float* l_out_w   = (const float*)d_in[13];
  const float* l_out_b   = (const float*)d_in[14];
  const float* halt_w    = (const float*)d_in[15];
  const float* halt_b    = (const float*)d_in[16];
  const float* reset_w   = (const float*)d_in[17];
  const float* reset_b   = (const float*)d_in[18];
  const float* l_init_w  = (const float*)d_in[19];
  const float* l_init_b  = (const float*)d_in[20];

  float* ws      = (float*)d_ws;
  float* cat     = ws + OFF_CAT;       // h = cat, l = cat+HH, conv = cat+HH+DD
  float* gi_h    = ws + OFF_GI_H;
  float* gh_h    = ws + OFF_GH_H;
  float* gi_l    = ws + OFF_GI_L;
  float* gh_l    = ws + OFF_GH_L;
  float* dir     = ws + OFF_DIR;
  float* res     = ws + OFF_RES;
  float* result  = ws + OFF_RESULT;
  float* scal    = ws + OFF_SCAL;
  float* g_act   = scal + 4;           // active flag
  float* g_rst   = scal + 5;           // do_reset flag

  const float4* q4 = (const float4*)query;
  const float4* h4 = (const float4*)cat;
  const float4* l4 = (const float4*)(cat + HH);
  const float4* d4 = (const float4*)dir;

  k_init<<<25, 256, 0, stream>>>(ws);

  for (int step = 0; step < NSTEPS; ++step) {
    if (step % KK == 0) {
      // h-GRU: 24576 wave-rows -> 6144 blocks
      k_hgru_mm<<<6144, 256, 0, stream>>>(h_gru_wih, h_gru_whh, q4, l4, h4,
                                          h_gru_bih, h_gru_bhh, gi_h, gh_h, g_act);
      k_gru_combine<<<16, 256, 0, stream>>>(gi_h, gh_h, cat, HH, g_act);
    }
    // directive = tanh(h_dir_w @ h + b): 2048 rows x 4096 cols
    k_matvec<<<512, 256, 0, stream>>>(h_dir_w, h4, h_dir_b, dir, DD, 1024, 1, g_act);
    // l-GRU matvecs: 12288 wave-rows -> 3072 blocks, 2048 cols
    k_lgru_mm<<<3072, 256, 0, stream>>>(l_gru_wih, l_gru_whh, d4, l4,
                                        l_gru_bih, l_gru_bhh, gi_l, gh_l, g_act);
    k_gru_combine<<<8, 256, 0, stream>>>(gi_l, gh_l, cat + HH, DD, g_act);
    // res = tanh(l_out_w @ l + b): 2048 rows x 2048 cols
    k_matvec<<<512, 256, 0, stream>>>(l_out_w, l4, l_out_b, res, DD, 512, 1, g_act);
    // scalars + result accumulation
    k_finalize<<<1, 256, 0, stream>>>(cat, res, h_conv_w, h_conv_b, halt_w, halt_b,
                                      reset_w, reset_b, scal, result, step);
    if (step > KK) {
      // l = tanh(l_init_w @ h + b) when do_reset: 2048 rows x 4096 cols
      k_matvec<<<512, 256, 0, stream>>>(l_init_w, h4, l_init_b, cat + HH, DD, 1024, 1, g_rst);
    }
  }
  k_out<<<8, 256, 0, stream>>>(result, scal, (float*)d_out);
}